// Round 8
// baseline (409.687 us; speedup 1.0000x reference)
//
#include <hip/hip_runtime.h>

// CausalAttention: B=8, S=2048, D_IN=D_OUT=1024, single head, causal, fp32 I/O.
// Pipeline (all fp16 MFMA 16x16x32, fp32 accum):
//   1. cast x -> xh (fp16); transpose+cast Wq,Wk,Wv -> WT (d_out-major, fp16)
//   2. ca_qkv3: fused QKV GEMM.   3. ca_score2: U = exp(QK^T/32), 256^2 tiles
//   4. ca_rowsum: invl = 1/sum    5. ca_pv2: out = (U @ V) * invl
//
// R12 engine: single-barrier mod-4 parity ring (replaces the 4-phase/9-barrier
// structure that plateaued at MfmaUtil 37-40% across R8/R9/R10):
//  - BK=32 K-tiles; LDS = 16 slots x 8KB (128 KiB): parity p=t&3 holds tile
//    t's {A0,A1,B0,B1} at slots p*4+{0,1,2,3}.
//  - Tile t: read parity t&3; stage tile t+2 into parity (t+2)&3 (distance-2
//    prefetch); ONE gate per tile: s_waitcnt vmcnt(4) + s_barrier (waits only
//    on >=1.5-tile-old loads ~4000cyc slack; leaves t+2's 4 GLLs in flight).
//    Final two tiles gate vmcnt(0).
//  - NO intra-tile barriers / forced lgkm drains: compiler inserts fine-
//    grained lgkmcnt before each dependent MFMA and pipelines ds_reads under
//    MFMA. Safety: ds_read/GLL *issue* confined to the tile by the boundary
//    asm memory clobbers; within a window, stage parity (t+2)&3 differs from
//    both readable parities {t&3,(t+3)&3}; ds_read samples LDS at issue.
//  - Swizzle (64B-row slots): read chunk = quad ^ ((ll>>1)&3); stage source
//    logical chunk = (l&3)^((l>>3)&3); linear GLL dest -> 2-way free.
//  - NT in K32 units, must be %4==0 (qkv/score 32; pv (qt+1)*8). setprio
//    around MFMA clusters. Epilogues unchanged from R11.

#define Bv 8
#define Sv 2048
#define Dv 1024
#define NTQ 32  // K32 tiles in the QKV/score GEMMs (1024/32)

typedef _Float16 f16x8 __attribute__((ext_vector_type(8)));
typedef _Float16 f16x4 __attribute__((ext_vector_type(4)));
typedef float    f32x4 __attribute__((ext_vector_type(4)));

#define GLL(gp, lp)                                            \
  __builtin_amdgcn_global_load_lds(                            \
      (const __attribute__((address_space(1))) void*)(gp),     \
      (__attribute__((address_space(3))) void*)(lp), 16, 0, 0)

// --- 1a. cast x (fp32) -> fp16, 8 elems/thread ---
__global__ __launch_bounds__(256) void ca_cast(const float* __restrict__ x,
                                               _Float16* __restrict__ y) {
  int i = (blockIdx.x * 256 + threadIdx.x) * 8;
  f32x4 a = *(const f32x4*)(x + i);
  f32x4 b = *(const f32x4*)(x + i + 4);
  f16x8 h;
#pragma unroll
  for (int j = 0; j < 4; ++j) { h[j] = (_Float16)a[j]; h[4 + j] = (_Float16)b[j]; }
  *(f16x8*)(y + i) = h;
}

// --- 1b. transpose+cast W (K x N fp32) -> WT (N x K fp16) ---
__global__ __launch_bounds__(256) void ca_transpose(const float* __restrict__ W0,
                                                    const float* __restrict__ W1,
                                                    const float* __restrict__ W2,
                                                    _Float16* __restrict__ T0,
                                                    _Float16* __restrict__ T1,
                                                    _Float16* __restrict__ T2) {
  const float* W = blockIdx.z == 0 ? W0 : blockIdx.z == 1 ? W1 : W2;
  _Float16* WT   = blockIdx.z == 0 ? T0 : blockIdx.z == 1 ? T1 : T2;
  __shared__ _Float16 t[32][33];
  int k0 = blockIdx.x * 32, n0 = blockIdx.y * 32;
  int r = threadIdx.x >> 5, c = threadIdx.x & 31;
#pragma unroll
  for (int i = 0; i < 4; ++i)
    t[r + i * 8][c] = (_Float16)W[(size_t)(k0 + r + i * 8) * Dv + n0 + c];
  __syncthreads();
#pragma unroll
  for (int i = 0; i < 4; ++i)
    WT[(size_t)(n0 + r + i * 8) * Dv + k0 + c] = t[c][r + i * 8];
}

// ---------------------------------------------------------------------------
// R12 single-barrier 256x256 GEMM engine.  A: [256 x K] row-major (ldA),
// B: [256 x K] row-major (ldB), C += A @ B^T over K = NTt*32 (NTt % 4 == 0).
// Caller provides L (16 x 4096 f16 = 128 KiB) and acc[8][4] (zeroed).
// On return: no GLLs outstanding; all waves past the final barrier.
// ---------------------------------------------------------------------------
__device__ __forceinline__ void gemm_fine(const _Float16* __restrict__ gA, int ldA,
                                          const _Float16* __restrict__ gB, long ldB,
                                          int NTt, _Float16 (*L)[4096],
                                          f32x4 acc[8][4]) {
  const int tid  = threadIdx.x;
  const int lane = tid & 63, wave = tid >> 6;
  const int wm = wave >> 2, wn = wave & 3;          // 2M x 4N waves, tile 128x64
  const int ll = lane & 15, quad = lane >> 4;

  // staging geometry: one GLL per wave per 8KB slot (512thr x 16B = 8KB).
  // thread t covers slot row t>>2, phys chunk t&3; pre-swizzled source
  // logical chunk = (l&3) ^ ((l>>3)&3)  (wave*16 rows keep (row>>1)&3 = fn(l)).
  const int sRow = wave * 16 + (lane >> 2);
  const int sCol = (((lane & 3) ^ ((lane >> 3) & 3)) << 3);  // elems
  const long aOff = (long)sRow * ldA + sCol;
  const long bOff = (long)sRow * ldB + sCol;
  _Float16* Ldst = &L[0][0] + wave * 512;           // wave-uniform (elems)

  // read geometry: slot row r, frag chunk quad -> phys chunk quad^((r>>1)&3),
  // and (r>>1)&3 == (ll>>1)&3 for all our rows (higher bits are *16/*64).
  const int swz = ((quad ^ ((ll >> 1) & 3)) << 3);  // elems
  _Float16* Lb = &L[0][0];
  const _Float16* pA = Lb + wm * 4096 + ll * 32 + swz;                       // + d*16384 + (mh*4+i)*512
  const _Float16* pB = Lb + 8192 + (wn >> 1) * 4096 + ((wn & 1) * 64 + ll) * 32 + swz;  // + d*16384 + i*512

#define STGA(p, ht, kpf)                                          \
  GLL(gA + (long)(ht) * 128 * ldA + (kpf) * 32 + aOff,            \
      Ldst + ((p) * 4 + (ht)) * 4096)
#define STGB(p, ht, kpf)                                          \
  GLL(gB + (long)(ht) * 128 * ldB + (kpf) * 32 + bOff,            \
      Ldst + ((p) * 4 + 2 + (ht)) * 4096)
#define RD_A(arr, d, mh)                                          \
  _Pragma("unroll") for (int i_ = 0; i_ < 4; ++i_)                \
      arr[i_] = *(const f16x8*)(pA + (d) * 16384 + ((mh) * 4 + i_) * 512);
#define RD_B(arr, d)                                              \
  _Pragma("unroll") for (int i_ = 0; i_ < 4; ++i_)                \
      arr[i_] = *(const f16x8*)(pB + (d) * 16384 + i_ * 512);
#define MMA(arr, mh)                                              \
  __builtin_amdgcn_s_setprio(1);                                  \
  _Pragma("unroll") for (int i_ = 0; i_ < 4; ++i_)                \
  _Pragma("unroll") for (int j_ = 0; j_ < 4; ++j_)                \
      acc[(mh) * 4 + i_][j_] = __builtin_amdgcn_mfma_f32_16x16x32_f16( \
          arr[i_], b[j_], acc[(mh) * 4 + i_][j_], 0, 0, 0);       \
  __builtin_amdgcn_s_setprio(0);
#define BAR() __builtin_amdgcn_s_barrier()
#define WAITV_(n) asm volatile("s_waitcnt vmcnt(" #n ")" ::: "memory")
#define WAITV(n) WAITV_(n)

  // Tile (kk, parity d, gate G): reads parity d (12 ds_read_b128), stages
  // tile kk+2 into parity (d+2)&3 (4 GLLs), 32 MFMA, one WAITV(G)+BAR.
#define TILE(kk, d, G)                                            \
  do {                                                            \
    f16x8 a0[4], a1[4], b[4];                                     \
    RD_A(a0, d, 0); RD_B(b, d);                                   \
    if ((kk) + 2 < NTt) {                                         \
      STGA(((d) + 2) & 3, 0, (kk) + 2);                           \
      STGA(((d) + 2) & 3, 1, (kk) + 2);                           \
    }                                                             \
    MMA(a0, 0);                                                   \
    RD_A(a1, d, 1);                                               \
    if ((kk) + 2 < NTt) {                                         \
      STGB(((d) + 2) & 3, 0, (kk) + 2);                           \
      STGB(((d) + 2) & 3, 1, (kk) + 2);                           \
    }                                                             \
    MMA(a1, 1);                                                   \
    WAITV(G); BAR();                                              \
  } while (0)

  // Prologue: stage tiles 0 (parity 0) and 1 (parity 1); gate vmcnt(4)
  // (tile 0's halves forced complete, tile 1's stay in flight).
  STGA(0, 0, 0); STGA(0, 1, 0); STGB(0, 0, 0); STGB(0, 1, 0);
  STGA(1, 0, 1); STGA(1, 1, 1); STGB(1, 0, 1); STGB(1, 1, 1);
  WAITV(4); BAR();

#pragma unroll 1
  for (int kk = 0; kk + 4 < NTt; kk += 4) {
    TILE(kk, 0, 4); TILE(kk + 1, 1, 4); TILE(kk + 2, 2, 4); TILE(kk + 3, 3, 4);
  }
  {
    const int kk = NTt - 4;   // NTt % 4 == 0
    TILE(kk, 0, 4); TILE(kk + 1, 1, 4); TILE(kk + 2, 2, 0); TILE(kk + 3, 3, 0);
  }

#undef TILE
#undef MMA
#undef RD_A
#undef RD_B
#undef STGB
#undef STGA
}

#define ZERO8x4(acc)                               \
  _Pragma("unroll") for (int i_ = 0; i_ < 8; ++i_) \
  _Pragma("unroll") for (int j_ = 0; j_ < 4; ++j_) \
      acc[i_][j_] = (f32x4){0.f, 0.f, 0.f, 0.f};

// Epilogue LDS scratch (64KB of L): swizzled f16 half-tile [128 rows][256 c].
#define USW(rowl, colb) ((rowl) * 256 + ((((colb) >> 3) ^ ((rowl) & 7)) << 3) + ((colb) & 7))

// ---------------------------------------------------------------------------
// --- 2. fused QKV projection: 768 blocks x 512 thr.
// nt = 0..11 of 256 cols: 0-3 Q, 4-7 K, 8-11 V.
// ---------------------------------------------------------------------------
__global__ __launch_bounds__(512, 2) void ca_qkv3(const _Float16* __restrict__ X,
                                                  const _Float16* __restrict__ WTq,
                                                  const _Float16* __restrict__ WTk,
                                                  const _Float16* __restrict__ WTv,
                                                  _Float16* __restrict__ Q,
                                                  _Float16* __restrict__ K,
                                                  _Float16* __restrict__ Vt) {
  __shared__ _Float16 L[16][4096];

  // XCD-chunked bijective swizzle: 768 % 8 == 0.
  int id  = blockIdx.x;
  int swzb = (id & 7) * 96 + (id >> 3);
  int my  = swzb / 12, nt = swzb - my * 12;
  int m0  = my * 256;
  int which = nt >> 2;
  int n0  = (nt & 3) * 256;
  const _Float16* WT = which == 0 ? WTq : which == 1 ? WTk : WTv;

  f32x4 acc[8][4];
  ZERO8x4(acc);
  gemm_fine(X + (size_t)m0 * Dv, Dv, WT + (size_t)n0 * Dv, Dv, NTQ, L, acc);

  const int tid = threadIdx.x;
  const int lane = tid & 63, wave = tid >> 6;
  const int wm = wave >> 2, wn = wave & 3;
  const int ll = lane & 15, quad = lane >> 4;
  if (which < 2) {
    // Q/K: LDS-transpose epilogue -> coalesced f16x8 row-major stores.
    _Float16* Us = &L[0][0];
    _Float16* Out = which == 0 ? Q : K;
#pragma unroll
    for (int h = 0; h < 2; ++h) {
      __builtin_amdgcn_s_barrier();
      if (wm == h) {
#pragma unroll
        for (int mi = 0; mi < 8; ++mi)
#pragma unroll
          for (int ni = 0; ni < 4; ++ni) {
            int colb = wn * 64 + ni * 16 + ll;
#pragma unroll
            for (int r = 0; r < 4; ++r) {
              int rowl = mi * 16 + quad * 4 + r;
              Us[USW(rowl, colb)] = (_Float16)acc[mi][ni][r];
            }
          }
      }
      __builtin_amdgcn_s_barrier();
#pragma unroll
      for (int j = 0; j < 8; ++j) {
        int idx = j * 4096 + tid * 8;
        int rowl = idx >> 8, col = idx & 255;
        f16x8 v = *(const f16x8*)(Us + USW(rowl, col));
        *(f16x8*)(Out + (size_t)(m0 + h * 128 + rowl) * Dv + n0 + col) = v;
      }
    }
  } else {
    // Vt: [d_out][B*S]; 4 regs = 4 consecutive rows -> contiguous 8B store
#pragma unroll
    for (int mi = 0; mi < 8; ++mi)
#pragma unroll
      for (int ni = 0; ni < 4; ++ni) {
        int gc = n0 + wn * 64 + ni * 16 + ll;
        int gr = m0 + wm * 128 + mi * 16 + quad * 4;
        f16x4 v;
#pragma unroll
        for (int r = 0; r < 4; ++r) v[r] = (_Float16)acc[mi][ni][r];
        *(f16x4*)(Vt + (size_t)gc * (Bv * Sv) + gr) = v;
      }
  }
}

// ---------------------------------------------------------------------------
// --- 3. scores: U = exp(QK^T / 32), 256^2 tiles, causal blocks only ---
// grid (8,8,8): kt, qt, b.  288 active blocks (kt <= qt), NT=32.
// ---------------------------------------------------------------------------
__global__ __launch_bounds__(512, 2) void ca_score2(const _Float16* __restrict__ Q,
                                                    const _Float16* __restrict__ Km,
                                                    _Float16* __restrict__ U) {
  int kt = blockIdx.x, qt = blockIdx.y, b = blockIdx.z;
  if (kt > qt) return;
  __shared__ _Float16 L[16][4096];
  f32x4 acc[8][4];
  ZERO8x4(acc);
  const _Float16* Qb = Q + ((size_t)b * Sv + qt * 256) * Dv;
  const _Float16* Kb = Km + ((size_t)b * Sv + kt * 256) * Dv;
  gemm_fine(Qb, Dv, Kb, Dv, NTQ, L, acc);

  const int tid = threadIdx.x;
  const int lane = tid & 63, wave = tid >> 6;
  const int wm = wave >> 2, wn = wave & 3;
  const int ll = lane & 15, quad = lane >> 4;
  _Float16* Us = &L[0][0];
#pragma unroll
  for (int h = 0; h < 2; ++h) {
    __builtin_amdgcn_s_barrier();
    if (wm == h) {
#pragma unroll
      for (int mi = 0; mi < 8; ++mi)
#pragma unroll
        for (int ni = 0; ni < 4; ++ni) {
          int colb = wn * 64 + ni * 16 + ll;
          int kc = kt * 256 + colb;
#pragma unroll
          for (int r = 0; r < 4; ++r) {
            int rowl = mi * 16 + quad * 4 + r;
            int qr = qt * 256 + h * 128 + rowl;
            float s = acc[mi][ni][r] * 0.03125f;  // 1/sqrt(1024)
            float u = (kc > qr) ? 0.f : __expf(fminf(fmaxf(s, -15.f), 10.f));
            Us[USW(rowl, colb)] = (_Float16)u;
          }
        }
    }
    __builtin_amdgcn_s_barrier();
#pragma unroll
    for (int j = 0; j < 8; ++j) {
      int idx = j * 4096 + tid * 8;
      int rowl = idx >> 8, col = idx & 255;
      f16x8 v = *(const f16x8*)(Us + USW(rowl, col));
      *(f16x8*)(U + ((size_t)b * Sv + qt * 256 + h * 128 + rowl) * Sv + kt * 256 + col) = v;
    }
  }
}

// --- 4. row sums -> 1/l ---
__global__ __launch_bounds__(256) void ca_rowsum(const _Float16* __restrict__ U,
                                                 float* __restrict__ invl) {
  int rg = blockIdx.x;
  int b = rg >> 11, q = rg & (Sv - 1);
  int lim = ((q >> 7) + 1) << 7;
  const _Float16* row = U + ((size_t)b * Sv + q) * Sv;
  float s = 0.f;
  for (int k = threadIdx.x * 8; k < lim; k += 2048) {
    f16x8 v = *(const f16x8*)(row + k);
#pragma unroll
    for (int j = 0; j < 8; ++j) s += (float)v[j];
  }
#pragma unroll
  for (int o = 32; o >= 1; o >>= 1) s += __shfl_down(s, o);
  __shared__ float wsum[4];
  if ((threadIdx.x & 63) == 0) wsum[threadIdx.x >> 6] = s;
  __syncthreads();
  if (threadIdx.x == 0) invl[rg] = 1.f / (wsum[0] + wsum[1] + wsum[2] + wsum[3]);
}

// ---------------------------------------------------------------------------
// --- 5. PV GEMM: out = (U @ V) * invl, 256^2 tiles ---
// grid (4,8,8): nt, qt, b.  NT = (qt+1)*8 K32-tiles (%4==0, 8..64).
// ---------------------------------------------------------------------------
__global__ __launch_bounds__(512, 2) void ca_pv2(const _Float16* __restrict__ U,
                                                 const _Float16* __restrict__ Vt,
                                                 const float* __restrict__ invl,
                                                 float* __restrict__ Out) {
  int nt = blockIdx.x, qt = blockIdx.y, b = blockIdx.z;
  __shared__ _Float16 L[16][4096];
  f32x4 acc[8][4];
  ZERO8x4(acc);
  const _Float16* Ab = U + ((size_t)b * Sv + qt * 256) * Sv;
  const _Float16* Bb = Vt + (size_t)(nt * 256) * (Bv * Sv) + (size_t)b * Sv;
  gemm_fine(Ab, Sv, Bb, (long)Bv * Sv, (qt + 1) * 8, L, acc);

  const int lane = threadIdx.x & 63, wave = threadIdx.x >> 6;
  const int wm = wave >> 2, wn = wave & 3;
  const int ll = lane & 15, quad = lane >> 4;
#pragma unroll
  for (int mi = 0; mi < 8; ++mi)
#pragma unroll
    for (int ni = 0; ni < 4; ++ni) {
      int oc = nt * 256 + wn * 64 + ni * 16 + ll;
#pragma unroll
      for (int r = 0; r < 4; ++r) {
        int qr = qt * 256 + wm * 128 + mi * 16 + quad * 4 + r;
        Out[((size_t)b * Sv + qr) * Dv + oc] = acc[mi][ni][r] * invl[b * Sv + qr];
      }
    }
}

extern "C" void kernel_launch(void* const* d_in, const int* in_sizes, int n_in,
                              void* d_out, int out_size, void* d_ws, size_t ws_size,
                              hipStream_t stream) {
  const float* x  = (const float*)d_in[0];
  const float* Wq = (const float*)d_in[1];
  const float* Wk = (const float*)d_in[2];
  const float* Wv = (const float*)d_in[3];
  float* out = (float*)d_out;

  char* ws = (char*)d_ws;
  size_t off = 0;
  const size_t M = (size_t)Bv * Sv;           // 16384
  _Float16* xh  = (_Float16*)(ws + off); off += M * Dv * 2;        // 32 MB
  _Float16* WTq = (_Float16*)(ws + off); off += (size_t)Dv * Dv * 2;
  _Float16* WTk = (_Float16*)(ws + off); off += (size_t)Dv * Dv * 2;
  _Float16* WTv = (_Float16*)(ws + off); off += (size_t)Dv * Dv * 2;
  _Float16* Q   = (_Float16*)(ws + off); off += M * Dv * 2;        // 32 MB
  _Float16* Km  = (_Float16*)(ws + off); off += M * Dv * 2;        // 32 MB
  _Float16* Vt  = (_Float16*)(ws + off); off += M * Dv * 2;        // 32 MB (transposed)
  _Float16* U   = (_Float16*)(ws + off); off += (size_t)Bv * Sv * Sv * 2;  // 64 MB
  float*    invl = (float*)(ws + off);   off += M * 4;

  ca_cast<<<(M * Dv) / (8 * 256), 256, 0, stream>>>(x, xh);
  ca_transpose<<<dim3(32, 32, 3), 256, 0, stream>>>(Wq, Wk, Wv, WTq, WTk, WTv);

  ca_qkv3<<<dim3(768), 512, 0, stream>>>(xh, WTq, WTk, WTv, Q, Km, Vt);

  ca_score2<<<dim3(8, 8, Bv), 512, 0, stream>>>(Q, Km, U);
  ca_rowsum<<<M, 256, 0, stream>>>(U, invl);
  ca_pv2<<<dim3(4, 8, Bv), 512, 0, stream>>>(U, Vt, invl, out);
}

// Round 9
// 375.653 us; speedup vs baseline: 1.0906x; 1.0906x over previous
//
#include <hip/hip_runtime.h>

// CausalAttention: B=8, S=2048, D_IN=D_OUT=1024, single head, causal, fp32 I/O.
// Pipeline (all fp16 MFMA 16x16x32, fp32 accum):
//   1. cast x -> xh (fp16) + zero rsum; transpose+cast Wq,Wk,Wv -> WT
//   2. ca_qkv3: fused QKV GEMM (R8 fine-phase engine -- best measured, 360us)
//   3. ca_score2: U = exp(QK^T/32) + fused row-sum atomics (R13)
//   4. ca_pv2: out = (U @ V) / rsum, 256^2 tiles
//
// R13 = exact revert to the best-measured R8 configuration (Round-4 source,
// 360 us) + ONE change: ca_rowsum is fused into ca_score2.
//  - Four engine-schedule variants (4-phase R8, deep-prefetch R9, re-timed
//    R10, single-barrier ring R12) all plateaued at qkv ~112-120us /
//    MfmaUtil 37-41% -> sync pattern is not the lever; engine frozen at R8.
//  - rowsum re-read all 64MB of U (~10us) + a launch to compute sums score2
//    already has in registers. Now: per-thread Sum_ni (3 adds), 4-step
//    __shfl_xor reduce over the 16 same-row lanes, one atomicAdd per row per
//    wave (<=36 adds/row total -- negligible contention; f32 reorder ~1ulp).
//  - rsum zeroed by 16 blocks of ca_cast (stream-ordered, runs first).
//  - ca_pv2 computes 1/rsum inline (hoisted, 32 values/thread).
// Engine recap (R8): 256x256 tile, 512 thr / 8 waves (2Mx4N), BK=64 K-tiles,
// 4 phases/tile, 16 MFMA/phase, 2 barriers/phase; LDS = 8 half-slot ring
// (128 KiB, 2-tile dbuf); stages A0(t+1)@p0, A1(t+1)@p1, B1(t+1)@p2,
// B0(t+2)@p3; gate vmcnt(2) once/tile (vmcnt(0) only at tile NT-2); T2
// 16B-chunk XOR swizzle pc = c ^ (row&7) both sides; setprio around MFMA;
// PH_OPEN = {s_barrier; lgkmcnt(0); sched_barrier(0)}.

#define Bv 8
#define Sv 2048
#define Dv 1024
#define NTQ 16  // K64 tiles in the QKV/score GEMMs (1024/64)

typedef _Float16 f16x8 __attribute__((ext_vector_type(8)));
typedef _Float16 f16x4 __attribute__((ext_vector_type(4)));
typedef float    f32x4 __attribute__((ext_vector_type(4)));

#define GLL(gp, lp)                                            \
  __builtin_amdgcn_global_load_lds(                            \
      (const __attribute__((address_space(1))) void*)(gp),     \
      (__attribute__((address_space(3))) void*)(lp), 16, 0, 0)

// --- 1a. cast x (fp32) -> fp16, 8 elems/thread; blocks 0..15 zero rsum ---
__global__ __launch_bounds__(256) void ca_cast(const float* __restrict__ x,
                                               _Float16* __restrict__ y,
                                               float* __restrict__ rsum) {
  int i = (blockIdx.x * 256 + threadIdx.x) * 8;
  f32x4 a = *(const f32x4*)(x + i);
  f32x4 b = *(const f32x4*)(x + i + 4);
  f16x8 h;
#pragma unroll
  for (int j = 0; j < 4; ++j) { h[j] = (_Float16)a[j]; h[4 + j] = (_Float16)b[j]; }
  *(f16x8*)(y + i) = h;
  if (blockIdx.x < 16) {
    int j = blockIdx.x * 1024 + threadIdx.x * 4;   // 16*256*4 = 16384 = B*S
    *(f32x4*)(rsum + j) = (f32x4){0.f, 0.f, 0.f, 0.f};
  }
}

// --- 1b. transpose+cast W (K x N fp32) -> WT (N x K fp16) ---
__global__ __launch_bounds__(256) void ca_transpose(const float* __restrict__ W0,
                                                    const float* __restrict__ W1,
                                                    const float* __restrict__ W2,
                                                    _Float16* __restrict__ T0,
                                                    _Float16* __restrict__ T1,
                                                    _Float16* __restrict__ T2) {
  const float* W = blockIdx.z == 0 ? W0 : blockIdx.z == 1 ? W1 : W2;
  _Float16* WT   = blockIdx.z == 0 ? T0 : blockIdx.z == 1 ? T1 : T2;
  __shared__ _Float16 t[32][33];
  int k0 = blockIdx.x * 32, n0 = blockIdx.y * 32;
  int r = threadIdx.x >> 5, c = threadIdx.x & 31;
#pragma unroll
  for (int i = 0; i < 4; ++i)
    t[r + i * 8][c] = (_Float16)W[(size_t)(k0 + r + i * 8) * Dv + n0 + c];
  __syncthreads();
#pragma unroll
  for (int i = 0; i < 4; ++i)
    WT[(size_t)(n0 + r + i * 8) * Dv + k0 + c] = t[c][r + i * 8];
}

// ---------------------------------------------------------------------------
// R8 fine-phase 256x256 GEMM engine.  A: [256 x K] row-major (ldA),
// B: [256 x K] row-major (ldB), C += A @ B^T over K = NTt*64 (NTt even >= 4).
// Caller provides L (8 x 8192 f16 = 128 KiB) and acc[8][4] (zeroed).
// ---------------------------------------------------------------------------
__device__ __forceinline__ void gemm_fine(const _Float16* __restrict__ gA, int ldA,
                                          const _Float16* __restrict__ gB, long ldB,
                                          int NTt, _Float16 (*L)[8192],
                                          f32x4 acc[8][4]) {
  const int tid  = threadIdx.x;
  const int lane = tid & 63, wave = tid >> 6;
  const int wm = wave >> 2, wn = wave & 3;          // 2M x 4N waves, tile 128x64
  const int ll = lane & 15, quad = lane >> 4;

  // staging geometry (pre-swizzled global source; linear GLL dest)
  const int laneRow = wave * 8 + (lane >> 3);
  const int laneCol = (((lane & 7) ^ ((lane >> 3) & 7)) << 3);  // elems
  const long aOff0 = (long)laneRow * ldA + laneCol;
  const long aOff1 = (long)(64 + laneRow) * ldA + laneCol;
  const long bOff0 = (long)laneRow * ldB + laneCol;
  const long bOff1 = (long)(64 + laneRow) * ldB + laneCol;
  _Float16* Ldst = &L[0][0] + wave * 512;           // wave-uniform

  // read geometry: frag (row, ks): phys chunk = (ks*4+quad)^(ll&7)
  const int sw0 = ((quad ^ (ll & 7)) << 3);         // ks=0, elems
  _Float16* Lb = &L[0][0];
  const _Float16* pA0 = Lb + wm * 8192 + ll * 64 + sw0;
  const _Float16* pA1 = Lb + wm * 8192 + ll * 64 + (sw0 ^ 32);
  const _Float16* pB0 = Lb + 16384 + (wn >> 1) * 8192 + (wn & 1) * 4096 + ll * 64 + sw0;
  const _Float16* pB1 = Lb + 16384 + (wn >> 1) * 8192 + (wn & 1) * 4096 + ll * 64 + (sw0 ^ 32);

#define STGA(slot, ht, kpf)                                       \
  do {                                                            \
    const _Float16* g_ = gA + (long)(ht) * 128 * ldA + (long)(kpf) * 64; \
    GLL(g_ + aOff0, Ldst + (slot) * 8192);                        \
    GLL(g_ + aOff1, Ldst + (slot) * 8192 + 4096);                 \
  } while (0)
#define STGB(slot, ht, kpf)                                       \
  do {                                                            \
    const _Float16* g_ = gB + (long)(ht) * 128 * ldB + (long)(kpf) * 64; \
    GLL(g_ + bOff0, Ldst + (slot) * 8192);                        \
    GLL(g_ + bOff1, Ldst + (slot) * 8192 + 4096);                 \
  } while (0)
#define RD_A(P, d, mh)                                            \
  _Pragma("unroll") for (int i_ = 0; i_ < 4; ++i_)                \
      a[i_] = *(const f16x8*)((P) + (d) * 32768 + ((mh) * 4 + i_) * 1024);
#define RD_B(P, d)                                                \
  _Pragma("unroll") for (int i_ = 0; i_ < 4; ++i_)                \
      b[i_] = *(const f16x8*)((P) + (d) * 32768 + i_ * 1024);
#define MMA(mh)                                                   \
  __builtin_amdgcn_s_setprio(1);                                  \
  _Pragma("unroll") for (int i_ = 0; i_ < 4; ++i_)                \
  _Pragma("unroll") for (int j_ = 0; j_ < 4; ++j_)                \
      acc[(mh) * 4 + i_][j_] = __builtin_amdgcn_mfma_f32_16x16x32_f16( \
          a[i_], b[j_], acc[(mh) * 4 + i_][j_], 0, 0, 0);         \
  __builtin_amdgcn_s_setprio(0);
#define BAR() __builtin_amdgcn_s_barrier()
#define WAITV_(n) asm volatile("s_waitcnt vmcnt(" #n ")" ::: "memory")
#define WAITV(n) WAITV_(n)
#define PH_OPEN()                                                 \
  BAR();                                                          \
  asm volatile("s_waitcnt lgkmcnt(0)" ::: "memory");              \
  __builtin_amdgcn_sched_barrier(0)

  // Per tile (kk, parity d): 4 phases {ds_read; stage 1 half; PH_OPEN; MFMA;
  // bar}.  p0: A[mh0,ks0]+B[ks0], stage A0(kk+1);  p1: A[mh1,ks0], stage
  // A1(kk+1);  p2: A[mh0,ks1]+B[ks1], stage B1(kk+1);  p3: A[mh1,ks1], stage
  // B0(kk+2).  sched_barrier(0) before p3 pins its stage below p2's B-reads.
#define TILEG(kk, d, G)                                           \
  do {                                                            \
    f16x8 a[4], b[4];                                             \
    RD_A(pA0, d, 0); RD_B(pB0, d);                                \
    if ((kk) + 1 < NTt) STGA(4 * (1 - (d)) + 0, 0, (kk) + 1);     \
    PH_OPEN(); MMA(0); BAR();                                     \
    RD_A(pA0, d, 1);                                              \
    if ((kk) + 1 < NTt) STGA(4 * (1 - (d)) + 1, 1, (kk) + 1);     \
    PH_OPEN(); MMA(1); BAR();                                     \
    RD_A(pA1, d, 0); RD_B(pB1, d);                                \
    if ((kk) + 1 < NTt) STGB(4 * (1 - (d)) + 3, 1, (kk) + 1);     \
    PH_OPEN(); MMA(0); BAR();                                     \
    __builtin_amdgcn_sched_barrier(0);                            \
    RD_A(pA1, d, 1);                                              \
    if ((kk) + 2 < NTt) STGB(4 * (d) + 2, 0, (kk) + 2);           \
    PH_OPEN(); MMA(1);                                            \
    WAITV(G); BAR();                                              \
    __builtin_amdgcn_sched_barrier(0);                            \
  } while (0)

  // Prologue: stage B0(0),A0(0),A1(0),B1(0),B0(1) (oldest-first), gate.
  STGB(2, 0, 0);
  STGA(0, 0, 0);
  STGA(1, 1, 0);
  STGB(3, 1, 0);
  STGB(6, 0, 1);
  WAITV(2); BAR();
  __builtin_amdgcn_sched_barrier(0);

#pragma unroll 1
  for (int kk = 0; kk < NTt - 2; kk += 2) {   // tiles 0..NTt-3
    TILEG(kk, 0, 2);
    TILEG(kk + 1, 1, 2);
  }
  TILEG(NTt - 2, 0, 0);   // tail: drain fully once
  TILEG(NTt - 1, 1, 2);

#undef TILEG
#undef PH_OPEN
#undef MMA
#undef RD_A
#undef RD_B
#undef STGB
#undef STGA
}

#define ZERO8x4(acc)                               \
  _Pragma("unroll") for (int i_ = 0; i_ < 8; ++i_) \
  _Pragma("unroll") for (int j_ = 0; j_ < 4; ++j_) \
      acc[i_][j_] = (f32x4){0.f, 0.f, 0.f, 0.f};

// ---------------------------------------------------------------------------
// --- 2. fused QKV projection: 768 blocks x 512 thr.
// nt = 0..11 of 256 cols: 0-3 Q, 4-7 K, 8-11 V.
// ---------------------------------------------------------------------------
__global__ __launch_bounds__(512, 2) void ca_qkv3(const _Float16* __restrict__ X,
                                                  const _Float16* __restrict__ WTq,
                                                  const _Float16* __restrict__ WTk,
                                                  const _Float16* __restrict__ WTv,
                                                  _Float16* __restrict__ Q,
                                                  _Float16* __restrict__ K,
                                                  _Float16* __restrict__ Vt) {
  __shared__ _Float16 L[8][8192];

  // XCD-chunked bijective swizzle: 768 % 8 == 0.
  int id  = blockIdx.x;
  int swz = (id & 7) * 96 + (id >> 3);
  int my  = swz / 12, nt = swz - my * 12;
  int m0  = my * 256;
  int which = nt >> 2;
  int n0  = (nt & 3) * 256;
  const _Float16* WT = which == 0 ? WTq : which == 1 ? WTk : WTv;

  f32x4 acc[8][4];
  ZERO8x4(acc);
  gemm_fine(X + (size_t)m0 * Dv, Dv, WT + (size_t)n0 * Dv, Dv, NTQ, L, acc);

  const int lane = threadIdx.x & 63, wave = threadIdx.x >> 6;
  const int wm = wave >> 2, wn = wave & 3;
  const int ll = lane & 15, quad = lane >> 4;
  if (which < 2) {
    _Float16* Out = which == 0 ? Q : K;
#pragma unroll
    for (int mi = 0; mi < 8; ++mi)
#pragma unroll
      for (int ni = 0; ni < 4; ++ni) {
        int gc = n0 + wn * 64 + ni * 16 + ll;
#pragma unroll
        for (int r = 0; r < 4; ++r) {
          int gr = m0 + wm * 128 + mi * 16 + quad * 4 + r;
          Out[(size_t)gr * Dv + gc] = (_Float16)acc[mi][ni][r];
        }
      }
  } else {
    // Vt: [d_out][B*S]; 4 regs = 4 consecutive rows -> contiguous 8B store
#pragma unroll
    for (int mi = 0; mi < 8; ++mi)
#pragma unroll
      for (int ni = 0; ni < 4; ++ni) {
        int gc = n0 + wn * 64 + ni * 16 + ll;
        int gr = m0 + wm * 128 + mi * 16 + quad * 4;
        f16x4 v;
#pragma unroll
        for (int r = 0; r < 4; ++r) v[r] = (_Float16)acc[mi][ni][r];
        *(f16x4*)(Vt + (size_t)gc * (Bv * Sv) + gr) = v;
      }
  }
}

// ---------------------------------------------------------------------------
// --- 3. scores: U = exp(QK^T / 32), 256^2 tiles, causal blocks only,
//        fused row-sum: per-thread Sum_ni, shfl_xor reduce over the 16
//        same-row lanes, one atomicAdd per row per wave.
// grid (8,8,8): kt, qt, b.  288 active blocks (kt <= qt), NT=16.
// ---------------------------------------------------------------------------
__global__ __launch_bounds__(512, 2) void ca_score2(const _Float16* __restrict__ Q,
                                                    const _Float16* __restrict__ Km,
                                                    _Float16* __restrict__ U,
                                                    float* __restrict__ rsum) {
  int kt = blockIdx.x, qt = blockIdx.y, b = blockIdx.z;
  if (kt > qt) return;
  __shared__ _Float16 L[8][8192];
  f32x4 acc[8][4];
  ZERO8x4(acc);
  const _Float16* Qb = Q + ((size_t)b * Sv + qt * 256) * Dv;
  const _Float16* Kb = Km + ((size_t)b * Sv + kt * 256) * Dv;
  gemm_fine(Qb, Dv, Kb, Dv, NTQ, L, acc);

  const int lane = threadIdx.x & 63, wave = threadIdx.x >> 6;
  const int wm = wave >> 2, wn = wave & 3;
  const int ll = lane & 15, quad = lane >> 4;
  float psum[8][4];
#pragma unroll
  for (int mi = 0; mi < 8; ++mi)
#pragma unroll
    for (int r = 0; r < 4; ++r) psum[mi][r] = 0.f;

#pragma unroll
  for (int mi = 0; mi < 8; ++mi)
#pragma unroll
    for (int ni = 0; ni < 4; ++ni) {
      int kc = kt * 256 + wn * 64 + ni * 16 + ll;
#pragma unroll
      for (int r = 0; r < 4; ++r) {
        int qr = qt * 256 + wm * 128 + mi * 16 + quad * 4 + r;
        float s = acc[mi][ni][r] * 0.03125f;  // 1/sqrt(1024)
        float u = (kc > qr) ? 0.f : __expf(fminf(fmaxf(s, -15.f), 10.f));
        psum[mi][r] += u;
        U[((size_t)b * Sv + qr) * Sv + kc] = (_Float16)u;
      }
    }

  // row-sum reduce: lanes quad*16..quad*16+15 share a row; xor masks 1,2,4,8
  // stay inside the 16-lane group.
#pragma unroll
  for (int mi = 0; mi < 8; ++mi)
#pragma unroll
    for (int r = 0; r < 4; ++r) {
      float s = psum[mi][r];
      s += __shfl_xor(s, 1);
      s += __shfl_xor(s, 2);
      s += __shfl_xor(s, 4);
      s += __shfl_xor(s, 8);
      if (ll == 0) {
        int qr = qt * 256 + wm * 128 + mi * 16 + quad * 4 + r;
        atomicAdd(&rsum[(size_t)b * Sv + qr], s);
      }
    }
}

// ---------------------------------------------------------------------------
// --- 4. PV GEMM: out = (U @ V) / rsum, 256^2 tiles ---
// grid (4,8,8): nt, qt, b.  NT = (qt+1)*4 K64-tiles (even, 4..32).
// ---------------------------------------------------------------------------
__global__ __launch_bounds__(512, 2) void ca_pv2(const _Float16* __restrict__ U,
                                                 const _Float16* __restrict__ Vt,
                                                 const float* __restrict__ rsum,
                                                 float* __restrict__ Out) {
  int nt = blockIdx.x, qt = blockIdx.y, b = blockIdx.z;
  __shared__ _Float16 L[8][8192];
  f32x4 acc[8][4];
  ZERO8x4(acc);
  const _Float16* Ab = U + ((size_t)b * Sv + qt * 256) * Sv;
  const _Float16* Bb = Vt + (size_t)(nt * 256) * (Bv * Sv) + (size_t)b * Sv;
  gemm_fine(Ab, Sv, Bb, (long)Bv * Sv, (qt + 1) * 4, L, acc);

  const int lane = threadIdx.x & 63, wave = threadIdx.x >> 6;
  const int wm = wave >> 2, wn = wave & 3;
  const int ll = lane & 15, quad = lane >> 4;
  float il[8][4];
#pragma unroll
  for (int mi = 0; mi < 8; ++mi)
#pragma unroll
    for (int r = 0; r < 4; ++r) {
      int qr = qt * 256 + wm * 128 + mi * 16 + quad * 4 + r;
      il[mi][r] = 1.0f / rsum[(size_t)b * Sv + qr];
    }
#pragma unroll
  for (int mi = 0; mi < 8; ++mi)
#pragma unroll
    for (int ni = 0; ni < 4; ++ni) {
      int oc = nt * 256 + wn * 64 + ni * 16 + ll;
#pragma unroll
      for (int r = 0; r < 4; ++r) {
        int qr = qt * 256 + wm * 128 + mi * 16 + quad * 4 + r;
        Out[((size_t)b * Sv + qr) * Dv + oc] = acc[mi][ni][r] * il[mi][r];
      }
    }
}

extern "C" void kernel_launch(void* const* d_in, const int* in_sizes, int n_in,
                              void* d_out, int out_size, void* d_ws, size_t ws_size,
                              hipStream_t stream) {
  const float* x  = (const float*)d_in[0];
  const float* Wq = (const float*)d_in[1];
  const float* Wk = (const float*)d_in[2];
  const float* Wv = (const float*)d_in[3];
  float* out = (float*)d_out;

  char* ws = (char*)d_ws;
  size_t off = 0;
  const size_t M = (size_t)Bv * Sv;           // 16384
  _Float16* xh  = (_Float16*)(ws + off); off += M * Dv * 2;        // 32 MB
  _Float16* WTq = (_Float16*)(ws + off); off += (size_t)Dv * Dv * 2;
  _Float16* WTk = (_Float16*)(ws + off); off += (size_t)Dv * Dv * 2;
  _Float16* WTv = (_Float16*)(ws + off); off += (size_t)Dv * Dv * 2;
  _Float16* Q   = (_Float16*)(ws + off); off += M * Dv * 2;        // 32 MB
  _Float16* Km  = (_Float16*)(ws + off); off += M * Dv * 2;        // 32 MB
  _Float16* Vt  = (_Float16*)(ws + off); off += M * Dv * 2;        // 32 MB (transposed)
  _Float16* U   = (_Float16*)(ws + off); off += (size_t)Bv * Sv * Sv * 2;  // 64 MB
  float*    rsum = (float*)(ws + off);   off += M * 4;

  ca_cast<<<(M * Dv) / (8 * 256), 256, 0, stream>>>(x, xh, rsum);
  ca_transpose<<<dim3(32, 32, 3), 256, 0, stream>>>(Wq, Wk, Wv, WTq, WTk, WTv);

  ca_qkv3<<<dim3(768), 512, 0, stream>>>(xh, WTq, WTk, WTv, Q, Km, Vt);

  ca_score2<<<dim3(8, 8, Bv), 512, 0, stream>>>(Q, Km, U, rsum);
  ca_pv2<<<dim3(4, 8, Bv), 512, 0, stream>>>(U, Vt, rsum, out);
}